// Round 1
// 444.053 us; speedup vs baseline: 1.0352x; 1.0352x over previous
//
#include <hip/hip_runtime.h>
#include <hip/hip_bf16.h>
#include <stdint.h>

// MultiHeadedSelfAttention: B=2, L=4096, D=1024, H=1. fp32 inputs, FP32 output.
// Round 13: scores GEMM ported to 256x256/BK=64 8-phase schedule (T1+T2+T4+T5):
// counted vmcnt (never 0 in steady state), XOR-swizzled LDS via pre-swizzled
// global source, setprio around MFMA clusters, XCD-aware block swizzle.
// Everything else keeps the proven round-12 structure:
//   0. cast x (8192x1024), Wq, Wk, Wv, Wo -> bf16 (once)
//   1. Q  = x @ Wq^T          (8192x1024, K=1024)   grid 512   [gemm_bt]
//   2. Kp = x @ Wk^T          (8192x1024)            grid 512   [gemm_bt]
//   3. Vt = Wv @ x^T          (1024x8192)            grid 512   [gemm_bt]
//   4. S_z = Q_z @ Kp_z^T/32  (2x 4096x4096, K=1024) grid 512   [gemm256_bt, NEW]
//   5. softmax rows (8192 rows)
//   6. O_z = P_z @ V_z        (BT with Vt+z*4096, ldb=8192) grid 512 -> into Q
//   7. out = O @ Wo^T -> FP32 d_out (M=8192)         grid 512
// ws (u16): xb 8.39M | W*b 4x1.05M | Q 8.39M | Kp 8.39M | Vt 8.39M | S 33.55M
// = 71,303,168 u16 = 136 MiB (layout proven safe in prior rounds).

typedef unsigned short u16;
typedef short short8 __attribute__((ext_vector_type(8)));
typedef float f32x4 __attribute__((ext_vector_type(4)));

__device__ __forceinline__ void async_ld16(void* lds, const void* g) {
  __builtin_amdgcn_global_load_lds(
      (const __attribute__((address_space(1))) unsigned int*)g,
      (__attribute__((address_space(3))) unsigned int*)lds,
      16, 0, 0);
}

__device__ __forceinline__ u16 f2bf(float f) {  // RNE
  unsigned u = __float_as_uint(f);
  u += 0x7FFFu + ((u >> 16) & 1u);
  return (u16)(u >> 16);
}

// fp32 -> bf16, 8 elems/thread. n must be a multiple of 8 (true here).
__global__ __launch_bounds__(256)
void cast_f32_bf16(const float* __restrict__ in, u16* __restrict__ out, int n) {
  const int i = (blockIdx.x * 256 + threadIdx.x) * 8;
  if (i >= n) return;
  float4 a = ((const float4*)(in + i))[0];
  float4 b = ((const float4*)(in + i))[1];
  uint4 o;
  o.x = (unsigned)f2bf(a.x) | ((unsigned)f2bf(a.y) << 16);
  o.y = (unsigned)f2bf(a.z) | ((unsigned)f2bf(a.w) << 16);
  o.z = (unsigned)f2bf(b.x) | ((unsigned)f2bf(b.y) << 16);
  o.w = (unsigned)f2bf(b.z) | ((unsigned)f2bf(b.w) << 16);
  *(uint4*)(out + i) = o;
}

#define BM 128
#define BN 128
#define BK 32

// C(MxN, ldc) = scale * A(MxK, lda) @ Bt(NxK, ldb)^T. A,Bt bf16; fp32 accum.
// m97-structure 128x128 kernel (kept for N=1024 GEMMs where 256^2 under-fills).
__global__ __launch_bounds__(256)
void gemm_bt(const u16* __restrict__ A, const u16* __restrict__ Bt,
             void* __restrict__ Cv, int K, int lda, int ldb, int ldc,
             long long sAz, long long sBz, long long sCz,
             float scale, int store_f32) {
  __shared__ u16 As[BM * BK];
  __shared__ u16 Bs[BN * BK];

  A  += (long long)blockIdx.z * sAz;
  Bt += (long long)blockIdx.z * sBz;

  const int tid  = threadIdx.x;
  const int wave = tid >> 6;
  const int lane = tid & 63;
  const int wm   = wave >> 1;      // 0..1: wave row in 2x2
  const int wn   = wave & 1;       // 0..1: wave col
  const int r15  = lane & 15;
  const int q4   = lane >> 4;      // 0..3

  const int tileM = blockIdx.y * BM;
  const int tileN = blockIdx.x * BN;

  const int srow = tid >> 2;             // 0..63
  const int scol = (tid & 3) * 8;        // 0,8,16,24

  const u16* Aptr = A + (long long)tileM * lda;
  const u16* Bptr = Bt + (long long)tileN * ldb;

  f32x4 zero = {0.f, 0.f, 0.f, 0.f};
  f32x4 acc[4][4];
#pragma unroll
  for (int i = 0; i < 4; ++i)
#pragma unroll
    for (int j = 0; j < 4; ++j) acc[i][j] = zero;

  for (int k0 = 0; k0 < K; k0 += BK) {
    async_ld16(&As[tid * 8],        Aptr + (long long)srow * lda + k0 + scol);
    async_ld16(&As[2048 + tid * 8], Aptr + (long long)(srow + 64) * lda + k0 + scol);
    async_ld16(&Bs[tid * 8],        Bptr + (long long)srow * ldb + k0 + scol);
    async_ld16(&Bs[2048 + tid * 8], Bptr + (long long)(srow + 64) * ldb + k0 + scol);
    __syncthreads();

    short8 af[4], bf[4];
#pragma unroll
    for (int i = 0; i < 4; ++i)
      af[i] = *(const short8*)&As[(wm * 64 + i * 16 + r15) * BK + q4 * 8];
#pragma unroll
    for (int i = 0; i < 4; ++i)
      bf[i] = *(const short8*)&Bs[(wn * 64 + i * 16 + r15) * BK + q4 * 8];

#pragma unroll
    for (int i = 0; i < 4; ++i)
#pragma unroll
      for (int j = 0; j < 4; ++j)
        acc[i][j] = __builtin_amdgcn_mfma_f32_16x16x32_bf16(af[i], bf[j], acc[i][j], 0, 0, 0);

    __syncthreads();
  }

  // epilogue: C/D layout col = lane&15, row = q4*4 + reg  [e2e-verified]
#pragma unroll
  for (int i = 0; i < 4; ++i) {
#pragma unroll
    for (int j = 0; j < 4; ++j) {
      const int col = tileN + wn * 64 + j * 16 + r15;
#pragma unroll
      for (int r = 0; r < 4; ++r) {
        const int row = tileM + wm * 64 + i * 16 + q4 * 4 + r;
        const long long idx = (long long)blockIdx.z * sCz + (long long)row * ldc + col;
        const float val = acc[i][j][r] * scale;
        if (store_f32) ((float*)Cv)[idx] = val;
        else           ((u16*)Cv)[idx] = f2bf(val);
      }
    }
  }
}

// ---------------------------------------------------------------------------
// 256x256 / BK=64 / 8-wave (2Mx4N) / 512-thread 8-phase GEMM (scores only).
// C = scale * A @ Bt^T, bf16 in/out, z-batched. K must be a multiple of 64.
// LDS 128 KiB: [dbuf:2][A|B][half:2][128 rows x 64 cols bf16], linear layout,
// XOR-swizzle ((row&7)<<4 on byte offset) realized by pre-swizzling the
// GLOBAL source column (global_load_lds writes linearly) and applying the
// same XOR on the ds_read address. Counted vmcnt(4) at K-tile boundaries.
// ---------------------------------------------------------------------------
__global__ __launch_bounds__(512)
void gemm256_bt(const u16* __restrict__ A, const u16* __restrict__ Bt,
                u16* __restrict__ C, int K, int lda, int ldb, int ldc,
                long long sAz, long long sBz, long long sCz, float scale) {
  __shared__ u16 smem[65536];  // 128 KiB

  // T1: bijective XCD swizzle over the whole grid (nwg=512, %8==0).
  const int nwg = gridDim.x * gridDim.y * gridDim.z;
  const int lin = (blockIdx.z * gridDim.y + blockIdx.y) * gridDim.x + blockIdx.x;
  const int chunk = nwg >> 3;
  const int swz = (lin & 7) * chunk + (lin >> 3);
  const int bx = swz % gridDim.x;
  const int t1 = swz / gridDim.x;
  const int by = t1 % gridDim.y;
  const int bz = t1 / gridDim.y;

  A  += (long long)bz * sAz;
  Bt += (long long)bz * sBz;
  const long long cbase = (long long)bz * sCz;

  const int tid  = threadIdx.x;
  const int wid  = tid >> 6;
  const int lane = tid & 63;
  const int wm   = wid >> 2;       // 0..1: wave M-half
  const int wn   = wid & 3;        // 0..3: wave N-quarter
  const int r15  = lane & 15;
  const int q4   = lane >> 4;

  const int tileM = by * 256;
  const int tileN = bx * 256;

  // staging geometry: thread covers 16B; half-tile (128x64) = 2 loads/thread.
  const int srow = tid >> 3;                        // 0..63
  const int scol = ((tid & 7) ^ (srow & 7)) * 8;    // pre-swizzled source col

  const u16* Ap = A  + (long long)(tileM + srow) * lda + scol;
  const u16* Bp = Bt + (long long)(tileN + srow) * ldb + scol;

  // stage one half-tile (2 x global_load_lds) of A or B for K-tile kt.
  auto stageA = [&](int kt, int half) {
    u16* dst = &smem[(kt & 1) * 32768 + half * 8192 + tid * 8];
    const u16* s = Ap + (long long)(half * 128) * lda + kt * 64;
    async_ld16(dst,        s);
    async_ld16(dst + 4096, s + 64 * lda);
  };
  auto stageB = [&](int kt, int half) {
    u16* dst = &smem[(kt & 1) * 32768 + 16384 + half * 8192 + tid * 8];
    const u16* s = Bp + (long long)(half * 128) * ldb + kt * 64;
    async_ld16(dst,        s);
    async_ld16(dst + 4096, s + 64 * ldb);
  };

  // per-lane read bases (swizzle XOR value is lane-constant: (r15&7)*8 elems)
  const int csw0 = (q4 * 8)      ^ ((r15 & 7) * 8);  // kh=0
  const int csw1 = (32 + q4 * 8) ^ ((r15 & 7) * 8);  // kh=1
  const u16* Aw = &smem[wm * 8192];
  const u16* Bw = &smem[16384 + (wn >> 1) * 8192 + (wn & 1) * 4096];

  f32x4 acc[8][4];
#pragma unroll
  for (int i = 0; i < 8; ++i)
#pragma unroll
    for (int j = 0; j < 4; ++j) acc[i][j] = (f32x4){0.f, 0.f, 0.f, 0.f};

  const int NT = K >> 6;

  // prologue: tile0 fully + tile1 A-halves (12 loads in flight)
  stageA(0, 0); stageA(0, 1); stageB(0, 0); stageB(0, 1);
  if (NT > 1) { stageA(1, 0); stageA(1, 1); }

  for (int j = 0; j < NT; ++j) {
    // wait for tile j's 8 loads; tile j+2's A-halves (4 loads) stay in flight.
    if (j + 1 < NT) asm volatile("s_waitcnt vmcnt(4)" ::: "memory");
    else            asm volatile("s_waitcnt vmcnt(0)" ::: "memory");
    __builtin_amdgcn_s_barrier();

    const u16* Ad = Aw + (j & 1) * 32768;
    const u16* Bd = Bw + (j & 1) * 32768;

#pragma unroll
    for (int q = 0; q < 4; ++q) {          // 4 quadrant phases per K-tile
      const int qm = q & 1, qn = q >> 1;

      short8 af[4][2], bf[2][2];
#pragma unroll
      for (int m2 = 0; m2 < 4; ++m2) {
        const int rb = ((qm * 4 + m2) * 16 + r15) * 64;
        af[m2][0] = *(const short8*)&Ad[rb + csw0];
        af[m2][1] = *(const short8*)&Ad[rb + csw1];
      }
#pragma unroll
      for (int n2 = 0; n2 < 2; ++n2) {
        const int rb = ((qn * 2 + n2) * 16 + r15) * 64;
        bf[n2][0] = *(const short8*)&Bd[rb + csw0];
        bf[n2][1] = *(const short8*)&Bd[rb + csw1];
      }

      // staged prefetch: B-halves of tile j+1 land in the other dbuf.
      if (q == 0 && j + 1 < NT) stageB(j + 1, 0);
      if (q == 1 && j + 1 < NT) stageB(j + 1, 1);

      __builtin_amdgcn_s_barrier();
      __builtin_amdgcn_s_setprio(1);
#pragma unroll
      for (int m2 = 0; m2 < 4; ++m2)
#pragma unroll
        for (int n2 = 0; n2 < 2; ++n2) {
          f32x4 c = acc[qm * 4 + m2][qn * 2 + n2];
          c = __builtin_amdgcn_mfma_f32_16x16x32_bf16(af[m2][0], bf[n2][0], c, 0, 0, 0);
          c = __builtin_amdgcn_mfma_f32_16x16x32_bf16(af[m2][1], bf[n2][1], c, 0, 0, 0);
          acc[qm * 4 + m2][qn * 2 + n2] = c;
        }
      __builtin_amdgcn_s_setprio(0);
      __builtin_amdgcn_s_barrier();
    }

    // buf[j&1] is free past the phase-4 barrier: prefetch tile j+2 A-halves.
    if (j + 2 < NT) { stageA(j + 2, 0); stageA(j + 2, 1); }
  }

  // epilogue: per wave 128x64; C/D layout col = lane&15, row = q4*4 + reg.
  const int crow = tileM + wm * 128 + q4 * 4;
  const int ccol = tileN + wn * 64 + r15;
#pragma unroll
  for (int mi = 0; mi < 8; ++mi)
#pragma unroll
    for (int nj = 0; nj < 4; ++nj)
#pragma unroll
      for (int r = 0; r < 4; ++r) {
        const long long row = crow + mi * 16 + r;
        C[cbase + row * ldc + (ccol + nj * 16)] = f2bf(acc[mi][nj][r] * scale);
      }
}

// In-place row softmax over 4096 bf16 columns. grid = rows, block = 256.
__global__ __launch_bounds__(256)
void softmax_rows(u16* __restrict__ S) {
  const int tid = threadIdx.x;
  u16* rp = S + (long long)blockIdx.x * 4096;

  uint4 a = ((const uint4*)rp)[tid * 2];
  uint4 b = ((const uint4*)rp)[tid * 2 + 1];
  unsigned w[8] = {a.x, a.y, a.z, a.w, b.x, b.y, b.z, b.w};
  float v[16];
#pragma unroll
  for (int i = 0; i < 8; ++i) {
    v[2 * i]     = __uint_as_float(w[i] << 16);
    v[2 * i + 1] = __uint_as_float(w[i] & 0xFFFF0000u);
  }

  float m = v[0];
#pragma unroll
  for (int i = 1; i < 16; ++i) m = fmaxf(m, v[i]);
#pragma unroll
  for (int o = 32; o > 0; o >>= 1) m = fmaxf(m, __shfl_xor(m, o));
  __shared__ float redm[4];
  __shared__ float reds[4];
  const int wave = tid >> 6;
  if ((tid & 63) == 0) redm[wave] = m;
  __syncthreads();
  m = fmaxf(fmaxf(redm[0], redm[1]), fmaxf(redm[2], redm[3]));

  float s = 0.f;
#pragma unroll
  for (int i = 0; i < 16; ++i) {
    v[i] = __expf(v[i] - m);
    s += v[i];
  }
#pragma unroll
  for (int o = 32; o > 0; o >>= 1) s += __shfl_xor(s, o);
  if ((tid & 63) == 0) reds[wave] = s;
  __syncthreads();
  s = (reds[0] + reds[1]) + (reds[2] + reds[3]);
  const float inv = 1.0f / s;

#pragma unroll
  for (int i = 0; i < 8; ++i)
    w[i] = (unsigned)f2bf(v[2 * i] * inv) | ((unsigned)f2bf(v[2 * i + 1] * inv) << 16);
  uint4 oa = {w[0], w[1], w[2], w[3]};
  uint4 ob = {w[4], w[5], w[6], w[7]};
  ((uint4*)rp)[tid * 2] = oa;
  ((uint4*)rp)[tid * 2 + 1] = ob;
}

extern "C" void kernel_launch(void* const* d_in, const int* in_sizes, int n_in,
                              void* d_out, int out_size, void* d_ws, size_t ws_size,
                              hipStream_t stream) {
  const float* x  = (const float*)d_in[0];   // (2,4096,1024) fp32, batch-major
  const float* Wq = (const float*)d_in[1];   // (1024,1024) fp32 (out,in)
  const float* Wk = (const float*)d_in[2];
  const float* Wv = (const float*)d_in[3];
  const float* Wo = (const float*)d_in[4];
  float* out = (float*)d_out;                // (2,4096,1024) FP32

  // ws layout (u16 units) — 136 MiB total
  u16* xb  = (u16*)d_ws;                     // 8192x1024
  u16* Wqb = xb  + 8388608;                  // 1024x1024
  u16* Wkb = Wqb + 1048576;
  u16* Wvb = Wkb + 1048576;
  u16* Wob = Wvb + 1048576;
  u16* Q   = Wob + 1048576;                  // 8192x1024
  u16* Kp  = Q   + 8388608;                  // 8192x1024
  u16* Vt  = Kp  + 8388608;                  // 1024x8192 (Vt[e][b*4096+l])
  u16* S   = Vt  + 8388608;                  // 2 x 4096x4096
  u16* O   = Q;                              // alias: Q dead after scores GEMM

  const dim3 blk(256);

  // 0: casts (once)
  cast_f32_bf16<<<dim3(4096), blk, 0, stream>>>(x,  xb,  8388608);
  cast_f32_bf16<<<dim3(512),  blk, 0, stream>>>(Wq, Wqb, 1048576);
  cast_f32_bf16<<<dim3(512),  blk, 0, stream>>>(Wk, Wkb, 1048576);
  cast_f32_bf16<<<dim3(512),  blk, 0, stream>>>(Wv, Wvb, 1048576);
  cast_f32_bf16<<<dim3(512),  blk, 0, stream>>>(Wo, Wob, 1048576);

  // 1,2: Q = x@Wq^T, Kp = x@Wk^T   (M=8192, N=1024, K=1024), 512 blocks
  gemm_bt<<<dim3(8, 64, 1), blk, 0, stream>>>(xb, Wqb, Q, 1024, 1024, 1024, 1024,
                                              0, 0, 0, 1.f, 0);
  gemm_bt<<<dim3(8, 64, 1), blk, 0, stream>>>(xb, Wkb, Kp, 1024, 1024, 1024, 1024,
                                              0, 0, 0, 1.f, 0);
  // 3: Vt = Wv@x^T   (M=1024, N=8192, K=1024) -> ldc=8192, 512 blocks
  gemm_bt<<<dim3(64, 8, 1), blk, 0, stream>>>(Wvb, xb, Vt, 1024, 1024, 1024, 8192,
                                              0, 0, 0, 1.f, 0);
  // 4: S_z = Q_z @ Kp_z^T / 32   (M=N=4096, K=1024), z=2 — 256^2 8-phase, 512 blocks
  gemm256_bt<<<dim3(16, 16, 2), dim3(512), 0, stream>>>(
      Q, Kp, S, 1024, 1024, 1024, 4096,
      4194304LL, 4194304LL, 16777216LL, 0.03125f);
  // 5: softmax in place, 8192 rows
  softmax_rows<<<dim3(8192), blk, 0, stream>>>(S);
  // 6: O_z = P_z @ V_z == BT(A=S_z (4096x4096), Bt=Vt+z*4096, ldb=8192), 512 blocks
  gemm_bt<<<dim3(8, 32, 2), blk, 0, stream>>>(S, Vt, O, 4096, 4096, 8192, 1024,
                                              16777216LL, 4096LL, 4194304LL, 1.f, 0);
  // 7: out = O @ Wo^T   (M=8192, N=1024, K=1024), FP32 store, 512 blocks
  gemm_bt<<<dim3(8, 64, 1), blk, 0, stream>>>(O, Wob, out, 1024, 1024, 1024, 1024,
                                              0, 0, 0, 1.f, 1);
}

// Round 2
// 441.708 us; speedup vs baseline: 1.0407x; 1.0053x over previous
//
#include <hip/hip_runtime.h>
#include <hip/hip_bf16.h>
#include <stdint.h>

// MultiHeadedSelfAttention: B=2, L=4096, D=1024, H=1. fp32 inputs, FP32 output.
// Round 14: gemm256_bt K-loop restructured: 2 barriers/tile (was 9), 24
// ds_read_b128/tile (was 48, af hoisted per M-half), counted vmcnt(4),
// straight-line body so hipcc interleaves MFMA with ds_read/stage issue.
// Buffer discipline unchanged from the verified round-13 kernel:
//   stages into buf[nxt] only after top barrier; A(j+2) into buf[cur] only
//   after the end-of-tile barrier; vmcnt(0) only on the final tile.
// Pipeline stages:
//   0. cast x (8192x1024), Wq, Wk, Wv, Wo -> bf16 (once)
//   1. Q  = x @ Wq^T          (8192x1024, K=1024)   grid 512   [gemm_bt]
//   2. Kp = x @ Wk^T          (8192x1024)            grid 512   [gemm_bt]
//   3. Vt = Wv @ x^T          (1024x8192)            grid 512   [gemm_bt]
//   4. S_z = Q_z @ Kp_z^T/32  (2x 4096x4096, K=1024) grid 512   [gemm256_bt]
//   5. softmax rows (8192 rows)
//   6. O_z = P_z @ V_z        (BT with Vt+z*4096, ldb=8192) grid 512 -> into Q
//   7. out = O @ Wo^T -> FP32 d_out (M=8192)         grid 512
// ws (u16): xb 8.39M | W*b 4x1.05M | Q 8.39M | Kp 8.39M | Vt 8.39M | S 33.55M
// = 71,303,168 u16 = 136 MiB (layout proven safe in prior rounds).

typedef unsigned short u16;
typedef short short8 __attribute__((ext_vector_type(8)));
typedef float f32x4 __attribute__((ext_vector_type(4)));

__device__ __forceinline__ void async_ld16(void* lds, const void* g) {
  __builtin_amdgcn_global_load_lds(
      (const __attribute__((address_space(1))) unsigned int*)g,
      (__attribute__((address_space(3))) unsigned int*)lds,
      16, 0, 0);
}

__device__ __forceinline__ u16 f2bf(float f) {  // RNE
  unsigned u = __float_as_uint(f);
  u += 0x7FFFu + ((u >> 16) & 1u);
  return (u16)(u >> 16);
}

// fp32 -> bf16, 8 elems/thread. n must be a multiple of 8 (true here).
__global__ __launch_bounds__(256)
void cast_f32_bf16(const float* __restrict__ in, u16* __restrict__ out, int n) {
  const int i = (blockIdx.x * 256 + threadIdx.x) * 8;
  if (i >= n) return;
  float4 a = ((const float4*)(in + i))[0];
  float4 b = ((const float4*)(in + i))[1];
  uint4 o;
  o.x = (unsigned)f2bf(a.x) | ((unsigned)f2bf(a.y) << 16);
  o.y = (unsigned)f2bf(a.z) | ((unsigned)f2bf(a.w) << 16);
  o.z = (unsigned)f2bf(b.x) | ((unsigned)f2bf(b.y) << 16);
  o.w = (unsigned)f2bf(b.z) | ((unsigned)f2bf(b.w) << 16);
  *(uint4*)(out + i) = o;
}

#define BM 128
#define BN 128
#define BK 32

// C(MxN, ldc) = scale * A(MxK, lda) @ Bt(NxK, ldb)^T. A,Bt bf16; fp32 accum.
// m97-structure 128x128 kernel (kept for N=1024 GEMMs where 256^2 under-fills).
__global__ __launch_bounds__(256)
void gemm_bt(const u16* __restrict__ A, const u16* __restrict__ Bt,
             void* __restrict__ Cv, int K, int lda, int ldb, int ldc,
             long long sAz, long long sBz, long long sCz,
             float scale, int store_f32) {
  __shared__ u16 As[BM * BK];
  __shared__ u16 Bs[BN * BK];

  A  += (long long)blockIdx.z * sAz;
  Bt += (long long)blockIdx.z * sBz;

  const int tid  = threadIdx.x;
  const int wave = tid >> 6;
  const int lane = tid & 63;
  const int wm   = wave >> 1;      // 0..1: wave row in 2x2
  const int wn   = wave & 1;       // 0..1: wave col
  const int r15  = lane & 15;
  const int q4   = lane >> 4;      // 0..3

  const int tileM = blockIdx.y * BM;
  const int tileN = blockIdx.x * BN;

  const int srow = tid >> 2;             // 0..63
  const int scol = (tid & 3) * 8;        // 0,8,16,24

  const u16* Aptr = A + (long long)tileM * lda;
  const u16* Bptr = Bt + (long long)tileN * ldb;

  f32x4 zero = {0.f, 0.f, 0.f, 0.f};
  f32x4 acc[4][4];
#pragma unroll
  for (int i = 0; i < 4; ++i)
#pragma unroll
    for (int j = 0; j < 4; ++j) acc[i][j] = zero;

  for (int k0 = 0; k0 < K; k0 += BK) {
    async_ld16(&As[tid * 8],        Aptr + (long long)srow * lda + k0 + scol);
    async_ld16(&As[2048 + tid * 8], Aptr + (long long)(srow + 64) * lda + k0 + scol);
    async_ld16(&Bs[tid * 8],        Bptr + (long long)srow * ldb + k0 + scol);
    async_ld16(&Bs[2048 + tid * 8], Bptr + (long long)(srow + 64) * ldb + k0 + scol);
    __syncthreads();

    short8 af[4], bf[4];
#pragma unroll
    for (int i = 0; i < 4; ++i)
      af[i] = *(const short8*)&As[(wm * 64 + i * 16 + r15) * BK + q4 * 8];
#pragma unroll
    for (int i = 0; i < 4; ++i)
      bf[i] = *(const short8*)&Bs[(wn * 64 + i * 16 + r15) * BK + q4 * 8];

#pragma unroll
    for (int i = 0; i < 4; ++i)
#pragma unroll
      for (int j = 0; j < 4; ++j)
        acc[i][j] = __builtin_amdgcn_mfma_f32_16x16x32_bf16(af[i], bf[j], acc[i][j], 0, 0, 0);

    __syncthreads();
  }

  // epilogue: C/D layout col = lane&15, row = q4*4 + reg  [e2e-verified]
#pragma unroll
  for (int i = 0; i < 4; ++i) {
#pragma unroll
    for (int j = 0; j < 4; ++j) {
      const int col = tileN + wn * 64 + j * 16 + r15;
#pragma unroll
      for (int r = 0; r < 4; ++r) {
        const int row = tileM + wm * 64 + i * 16 + q4 * 4 + r;
        const long long idx = (long long)blockIdx.z * sCz + (long long)row * ldc + col;
        const float val = acc[i][j][r] * scale;
        if (store_f32) ((float*)Cv)[idx] = val;
        else           ((u16*)Cv)[idx] = f2bf(val);
      }
    }
  }
}

// ---------------------------------------------------------------------------
// 256x256 / BK=64 / 8-wave (2Mx4N) / 512-thread GEMM (scores).
// C = scale * A @ Bt^T, bf16 in/out, z-batched. K must be a multiple of 64.
// LDS 128 KiB: [dbuf:2][A|B][half:2][128 rows x 64 cols bf16], linear layout,
// XOR-swizzle ((row&7)<<4 on byte offset) realized by pre-swizzling the
// GLOBAL source column (global_load_lds writes linearly) and applying the
// same XOR on the ds_read address.
// Schedule per K-tile (v2): vmcnt(4)+barrier | stage B(j+1) | read bf(all) +
// af(qm=0) | 32 MFMA | read af(qm=1) | 32 MFMA | barrier | stage A(j+2).
// 2 barriers + 24 ds_read_b128 per tile; vmcnt(0) only on the last tile.
// ---------------------------------------------------------------------------
__global__ __launch_bounds__(512)
void gemm256_bt(const u16* __restrict__ A, const u16* __restrict__ Bt,
                u16* __restrict__ C, int K, int lda, int ldb, int ldc,
                long long sAz, long long sBz, long long sCz, float scale) {
  __shared__ u16 smem[65536];  // 128 KiB

  // T1: bijective XCD swizzle over the whole grid (nwg=512, %8==0).
  const int nwg = gridDim.x * gridDim.y * gridDim.z;
  const int lin = (blockIdx.z * gridDim.y + blockIdx.y) * gridDim.x + blockIdx.x;
  const int chunk = nwg >> 3;
  const int swz = (lin & 7) * chunk + (lin >> 3);
  const int bx = swz % gridDim.x;
  const int t1 = swz / gridDim.x;
  const int by = t1 % gridDim.y;
  const int bz = t1 / gridDim.y;

  A  += (long long)bz * sAz;
  Bt += (long long)bz * sBz;
  const long long cbase = (long long)bz * sCz;

  const int tid  = threadIdx.x;
  const int wid  = tid >> 6;
  const int lane = tid & 63;
  const int wm   = wid >> 2;       // 0..1: wave M-half
  const int wn   = wid & 3;        // 0..3: wave N-quarter
  const int r15  = lane & 15;
  const int q4   = lane >> 4;

  const int tileM = by * 256;
  const int tileN = bx * 256;

  // staging geometry: thread covers 16B; half-tile (128x64) = 2 loads/thread.
  const int srow = tid >> 3;                        // 0..63
  const int scol = ((tid & 7) ^ (srow & 7)) * 8;    // pre-swizzled source col

  const u16* Ap = A  + (long long)(tileM + srow) * lda + scol;
  const u16* Bp = Bt + (long long)(tileN + srow) * ldb + scol;

  // stage one half-tile (2 x global_load_lds) of A or B for K-tile kt.
  auto stageA = [&](int kt, int half) {
    u16* dst = &smem[(kt & 1) * 32768 + half * 8192 + tid * 8];
    const u16* s = Ap + (long long)(half * 128) * lda + kt * 64;
    async_ld16(dst,        s);
    async_ld16(dst + 4096, s + 64 * lda);
  };
  auto stageB = [&](int kt, int half) {
    u16* dst = &smem[(kt & 1) * 32768 + 16384 + half * 8192 + tid * 8];
    const u16* s = Bp + (long long)(half * 128) * ldb + kt * 64;
    async_ld16(dst,        s);
    async_ld16(dst + 4096, s + 64 * ldb);
  };

  // per-lane read bases (swizzle XOR value is lane-constant: (r15&7)*8 elems)
  const int csw0 = (q4 * 8)      ^ ((r15 & 7) * 8);  // kh=0
  const int csw1 = (32 + q4 * 8) ^ ((r15 & 7) * 8);  // kh=1
  const u16* Aw = &smem[wm * 8192];
  const u16* Bw = &smem[16384 + (wn >> 1) * 8192 + (wn & 1) * 4096];

  f32x4 acc[8][4];
#pragma unroll
  for (int i = 0; i < 8; ++i)
#pragma unroll
    for (int j = 0; j < 4; ++j) acc[i][j] = (f32x4){0.f, 0.f, 0.f, 0.f};

  const int NT = K >> 6;

  // prologue: tile0 fully + tile1 A-halves (12 loads in flight)
  stageA(0, 0); stageA(0, 1); stageB(0, 0); stageB(0, 1);
  if (NT > 1) { stageA(1, 0); stageA(1, 1); }

  for (int j = 0; j < NT; ++j) {
    // wait for tile j's loads; tile j+2's A-halves (4 loads) stay in flight.
    if (j + 1 < NT) asm volatile("s_waitcnt vmcnt(4)" ::: "memory");
    else            asm volatile("s_waitcnt vmcnt(0)" ::: "memory");
    __builtin_amdgcn_s_barrier();

    const u16* Ad = Aw + (j & 1) * 32768;
    const u16* Bd = Bw + (j & 1) * 32768;

    // stage next tile's B halves early (into buf[nxt]; safe past top barrier).
    if (j + 1 < NT) { stageB(j + 1, 0); stageB(j + 1, 1); }

    // B fragments for the whole tile (both N-quadrants) + A for qm=0.
    short8 af[4][2], bf0[2][2], bf1[2][2];
#pragma unroll
    for (int n2 = 0; n2 < 2; ++n2) {
      const int rb0 = (n2 * 16 + r15) * 64;
      const int rb1 = ((2 + n2) * 16 + r15) * 64;
      bf0[n2][0] = *(const short8*)&Bd[rb0 + csw0];
      bf0[n2][1] = *(const short8*)&Bd[rb0 + csw1];
      bf1[n2][0] = *(const short8*)&Bd[rb1 + csw0];
      bf1[n2][1] = *(const short8*)&Bd[rb1 + csw1];
    }
#pragma unroll
    for (int m2 = 0; m2 < 4; ++m2) {
      const int rb = (m2 * 16 + r15) * 64;
      af[m2][0] = *(const short8*)&Ad[rb + csw0];
      af[m2][1] = *(const short8*)&Ad[rb + csw1];
    }

    __builtin_amdgcn_s_setprio(1);
#pragma unroll
    for (int m2 = 0; m2 < 4; ++m2)
#pragma unroll
      for (int n2 = 0; n2 < 2; ++n2) {
        f32x4 c0 = acc[m2][n2];
        c0 = __builtin_amdgcn_mfma_f32_16x16x32_bf16(af[m2][0], bf0[n2][0], c0, 0, 0, 0);
        c0 = __builtin_amdgcn_mfma_f32_16x16x32_bf16(af[m2][1], bf0[n2][1], c0, 0, 0, 0);
        acc[m2][n2] = c0;
        f32x4 c1 = acc[m2][2 + n2];
        c1 = __builtin_amdgcn_mfma_f32_16x16x32_bf16(af[m2][0], bf1[n2][0], c1, 0, 0, 0);
        c1 = __builtin_amdgcn_mfma_f32_16x16x32_bf16(af[m2][1], bf1[n2][1], c1, 0, 0, 0);
        acc[m2][2 + n2] = c1;
      }
    __builtin_amdgcn_s_setprio(0);

    // A fragments for qm=1 (rows 64..127); issue overlaps the MFMAs above.
#pragma unroll
    for (int m2 = 0; m2 < 4; ++m2) {
      const int rb = ((4 + m2) * 16 + r15) * 64;
      af[m2][0] = *(const short8*)&Ad[rb + csw0];
      af[m2][1] = *(const short8*)&Ad[rb + csw1];
    }

    __builtin_amdgcn_s_setprio(1);
#pragma unroll
    for (int m2 = 0; m2 < 4; ++m2)
#pragma unroll
      for (int n2 = 0; n2 < 2; ++n2) {
        f32x4 c0 = acc[4 + m2][n2];
        c0 = __builtin_amdgcn_mfma_f32_16x16x32_bf16(af[m2][0], bf0[n2][0], c0, 0, 0, 0);
        c0 = __builtin_amdgcn_mfma_f32_16x16x32_bf16(af[m2][1], bf0[n2][1], c0, 0, 0, 0);
        acc[4 + m2][n2] = c0;
        f32x4 c1 = acc[4 + m2][2 + n2];
        c1 = __builtin_amdgcn_mfma_f32_16x16x32_bf16(af[m2][0], bf1[n2][0], c1, 0, 0, 0);
        c1 = __builtin_amdgcn_mfma_f32_16x16x32_bf16(af[m2][1], bf1[n2][1], c1, 0, 0, 0);
        acc[4 + m2][2 + n2] = c1;
      }
    __builtin_amdgcn_s_setprio(0);

    // all waves done reading buf[cur] past this barrier.
    __builtin_amdgcn_s_barrier();
    if (j + 2 < NT) { stageA(j + 2, 0); stageA(j + 2, 1); }  // into buf[cur]
  }

  // epilogue: per wave 128x64; C/D layout col = lane&15, row = q4*4 + reg.
  const int crow = tileM + wm * 128 + q4 * 4;
  const int ccol = tileN + wn * 64 + r15;
#pragma unroll
  for (int mi = 0; mi < 8; ++mi)
#pragma unroll
    for (int nj = 0; nj < 4; ++nj)
#pragma unroll
      for (int r = 0; r < 4; ++r) {
        const long long row = crow + mi * 16 + r;
        C[cbase + row * ldc + (ccol + nj * 16)] = f2bf(acc[mi][nj][r] * scale);
      }
}

// In-place row softmax over 4096 bf16 columns. grid = rows, block = 256.
__global__ __launch_bounds__(256)
void softmax_rows(u16* __restrict__ S) {
  const int tid = threadIdx.x;
  u16* rp = S + (long long)blockIdx.x * 4096;

  uint4 a = ((const uint4*)rp)[tid * 2];
  uint4 b = ((const uint4*)rp)[tid * 2 + 1];
  unsigned w[8] = {a.x, a.y, a.z, a.w, b.x, b.y, b.z, b.w};
  float v[16];
#pragma unroll
  for (int i = 0; i < 8; ++i) {
    v[2 * i]     = __uint_as_float(w[i] << 16);
    v[2 * i + 1] = __uint_as_float(w[i] & 0xFFFF0000u);
  }

  float m = v[0];
#pragma unroll
  for (int i = 1; i < 16; ++i) m = fmaxf(m, v[i]);
#pragma unroll
  for (int o = 32; o > 0; o >>= 1) m = fmaxf(m, __shfl_xor(m, o));
  __shared__ float redm[4];
  __shared__ float reds[4];
  const int wave = tid >> 6;
  if ((tid & 63) == 0) redm[wave] = m;
  __syncthreads();
  m = fmaxf(fmaxf(redm[0], redm[1]), fmaxf(redm[2], redm[3]));

  float s = 0.f;
#pragma unroll
  for (int i = 0; i < 16; ++i) {
    v[i] = __expf(v[i] - m);
    s += v[i];
  }
#pragma unroll
  for (int o = 32; o > 0; o >>= 1) s += __shfl_xor(s, o);
  if ((tid & 63) == 0) reds[wave] = s;
  __syncthreads();
  s = (reds[0] + reds[1]) + (reds[2] + reds[3]);
  const float inv = 1.0f / s;

#pragma unroll
  for (int i = 0; i < 8; ++i)
    w[i] = (unsigned)f2bf(v[2 * i] * inv) | ((unsigned)f2bf(v[2 * i + 1] * inv) << 16);
  uint4 oa = {w[0], w[1], w[2], w[3]};
  uint4 ob = {w[4], w[5], w[6], w[7]};
  ((uint4*)rp)[tid * 2] = oa;
  ((uint4*)rp)[tid * 2 + 1] = ob;
}

extern "C" void kernel_launch(void* const* d_in, const int* in_sizes, int n_in,
                              void* d_out, int out_size, void* d_ws, size_t ws_size,
                              hipStream_t stream) {
  const float* x  = (const float*)d_in[0];   // (2,4096,1024) fp32, batch-major
  const float* Wq = (const float*)d_in[1];   // (1024,1024) fp32 (out,in)
  const float* Wk = (const float*)d_in[2];
  const float* Wv = (const float*)d_in[3];
  const float* Wo = (const float*)d_in[4];
  float* out = (float*)d_out;                // (2,4096,1024) FP32

  // ws layout (u16 units) — 136 MiB total
  u16* xb  = (u16*)d_ws;                     // 8192x1024
  u16* Wqb = xb  + 8388608;                  // 1024x1024
  u16* Wkb = Wqb + 1048576;
  u16* Wvb = Wkb + 1048576;
  u16* Wob = Wvb + 1048576;
  u16* Q   = Wob + 1048576;                  // 8192x1024
  u16* Kp  = Q   + 8388608;                  // 8192x1024
  u16* Vt  = Kp  + 8388608;                  // 1024x8192 (Vt[e][b*4096+l])
  u16* S   = Vt  + 8388608;                  // 2 x 4096x4096
  u16* O   = Q;                              // alias: Q dead after scores GEMM

  const dim3 blk(256);

  // 0: casts (once)
  cast_f32_bf16<<<dim3(4096), blk, 0, stream>>>(x,  xb,  8388608);
  cast_f32_bf16<<<dim3(512),  blk, 0, stream>>>(Wq, Wqb, 1048576);
  cast_f32_bf16<<<dim3(512),  blk, 0, stream>>>(Wk, Wkb, 1048576);
  cast_f32_bf16<<<dim3(512),  blk, 0, stream>>>(Wv, Wvb, 1048576);
  cast_f32_bf16<<<dim3(512),  blk, 0, stream>>>(Wo, Wob, 1048576);

  // 1,2: Q = x@Wq^T, Kp = x@Wk^T   (M=8192, N=1024, K=1024), 512 blocks
  gemm_bt<<<dim3(8, 64, 1), blk, 0, stream>>>(xb, Wqb, Q, 1024, 1024, 1024, 1024,
                                              0, 0, 0, 1.f, 0);
  gemm_bt<<<dim3(8, 64, 1), blk, 0, stream>>>(xb, Wkb, Kp, 1024, 1024, 1024, 1024,
                                              0, 0, 0, 1.f, 0);
  // 3: Vt = Wv@x^T   (M=1024, N=8192, K=1024) -> ldc=8192, 512 blocks
  gemm_bt<<<dim3(64, 8, 1), blk, 0, stream>>>(Wvb, xb, Vt, 1024, 1024, 1024, 8192,
                                              0, 0, 0, 1.f, 0);
  // 4: S_z = Q_z @ Kp_z^T / 32   (M=N=4096, K=1024), z=2 — 256^2 v2, 512 blocks
  gemm256_bt<<<dim3(16, 16, 2), dim3(512), 0, stream>>>(
      Q, Kp, S, 1024, 1024, 1024, 4096,
      4194304LL, 4194304LL, 16777216LL, 0.03125f);
  // 5: softmax in place, 8192 rows
  softmax_rows<<<dim3(8192), blk, 0, stream>>>(S);
  // 6: O_z = P_z @ V_z == BT(A=S_z (4096x4096), Bt=Vt+z*4096, ldb=8192), 512 blocks
  gemm_bt<<<dim3(8, 32, 2), blk, 0, stream>>>(S, Vt, O, 4096, 4096, 8192, 1024,
                                              16777216LL, 4096LL, 4194304LL, 1.f, 0);
  // 7: out = O @ Wo^T   (M=8192, N=1024, K=1024), FP32 store, 512 blocks
  gemm_bt<<<dim3(8, 64, 1), blk, 0, stream>>>(O, Wob, out, 1024, 1024, 1024, 1024,
                                              0, 0, 0, 1.f, 1);
}

// Round 3
// 404.054 us; speedup vs baseline: 1.1377x; 1.0932x over previous
//
#include <hip/hip_runtime.h>
#include <hip/hip_bf16.h>
#include <stdint.h>

// MultiHeadedSelfAttention: B=2, L=4096, D=1024, H=1. fp32 inputs, FP32 output.
// Round 15: gemm_bt rebuilt with double-buffered LDS + counted vmcnt(4)
// (never 0 until last tile) + (row&3) XOR bank-swizzle on both stage-source
// and ds_read (8-way -> 4-way conflict). Q and K projections merged into one
// N=2048 GEMM (Wqb/Wkb adjacent) -> grid 1024, ~4 blocks/CU co-residency.
// Buffer discipline identical to the verified gemm256-v2 protocol:
//   stage(k)->buf[k&1]; top: vmcnt(4)+barrier; reads+MFMA; end barrier;
//   stage(k+2)->buf[k&1] (safe: same parity buffer just fully read).
// Pipeline:
//   0. cast x, Wq, Wk, Wv, Wo -> bf16 (once)
//   1. QKp = x @ [Wq;Wk]^T    (8192x2048, K=1024)  grid 1024  [gemm_bt v2]
//   2. Vt  = Wv @ x^T          (1024x8192)          grid 512   [gemm_bt v2]
//   3. S_z = Q_z @ Kp_z^T/32   (2x 4096x4096)       grid 512   [gemm256_bt]
//   4. softmax rows (8192 rows)
//   5. O_z = P_z @ V_z         -> O into QKp region  grid 512   [gemm_bt v2]
//   6. out = O @ Wo^T -> FP32 d_out                  grid 512   [gemm_bt v2]
// ws (u16): xb 8.39M | W*b 4x1.05M | QKp 16.78M | Vt 8.39M | S 33.55M
// = 71,303,168 u16 = 136 MiB (same footprint as prior rounds).

typedef unsigned short u16;
typedef short short8 __attribute__((ext_vector_type(8)));
typedef float f32x4 __attribute__((ext_vector_type(4)));

__device__ __forceinline__ void async_ld16(void* lds, const void* g) {
  __builtin_amdgcn_global_load_lds(
      (const __attribute__((address_space(1))) unsigned int*)g,
      (__attribute__((address_space(3))) unsigned int*)lds,
      16, 0, 0);
}

__device__ __forceinline__ u16 f2bf(float f) {  // RNE
  unsigned u = __float_as_uint(f);
  u += 0x7FFFu + ((u >> 16) & 1u);
  return (u16)(u >> 16);
}

// fp32 -> bf16, 8 elems/thread. n must be a multiple of 8 (true here).
__global__ __launch_bounds__(256)
void cast_f32_bf16(const float* __restrict__ in, u16* __restrict__ out, int n) {
  const int i = (blockIdx.x * 256 + threadIdx.x) * 8;
  if (i >= n) return;
  float4 a = ((const float4*)(in + i))[0];
  float4 b = ((const float4*)(in + i))[1];
  uint4 o;
  o.x = (unsigned)f2bf(a.x) | ((unsigned)f2bf(a.y) << 16);
  o.y = (unsigned)f2bf(a.z) | ((unsigned)f2bf(a.w) << 16);
  o.z = (unsigned)f2bf(b.x) | ((unsigned)f2bf(b.y) << 16);
  o.w = (unsigned)f2bf(b.z) | ((unsigned)f2bf(b.w) << 16);
  *(uint4*)(out + i) = o;
}

#define BM 128
#define BN 128
#define BK 32

// C(MxN, ldc) = scale * A(MxK, lda) @ Bt(NxK, ldb)^T. A,Bt bf16; fp32 accum.
// v2: dbuf LDS (2x16KB), counted vmcnt(4), depth-2 prefetch, bank swizzle.
// Swizzle: LDS[r][j*8] holds G[r][(j^(r&3))*8]; read col-chunk = q4^(r15&3).
__global__ __launch_bounds__(256)
void gemm_bt(const u16* __restrict__ A, const u16* __restrict__ Bt,
             void* __restrict__ Cv, int K, int lda, int ldb, int ldc,
             long long sAz, long long sBz, long long sCz,
             float scale, int store_f32) {
  __shared__ u16 As[2][BM * BK];
  __shared__ u16 Bs[2][BN * BK];

  A  += (long long)blockIdx.z * sAz;
  Bt += (long long)blockIdx.z * sBz;

  const int tid  = threadIdx.x;
  const int wave = tid >> 6;
  const int lane = tid & 63;
  const int wm   = wave >> 1;      // 0..1: wave row in 2x2
  const int wn   = wave & 1;       // 0..1: wave col
  const int r15  = lane & 15;
  const int q4   = lane >> 4;      // 0..3

  const int tileM = blockIdx.y * BM;
  const int tileN = blockIdx.x * BN;

  const int srow = tid >> 2;                        // 0..63
  const int scol = ((tid & 3) ^ (srow & 3)) * 8;    // pre-swizzled source col

  const u16* Aptr = A + (long long)tileM * lda + scol;
  const u16* Bptr = Bt + (long long)tileN * ldb + scol;

  // stage K-tile kt into buf[kt&1] (4 x global_load_lds, linear LDS dest).
  auto stage = [&](int kt) {
    const int k0 = kt * BK;
    u16* as = &As[kt & 1][tid * 8];
    u16* bs = &Bs[kt & 1][tid * 8];
    async_ld16(as,        Aptr + (long long)srow * lda + k0);
    async_ld16(as + 2048, Aptr + (long long)(srow + 64) * lda + k0);
    async_ld16(bs,        Bptr + (long long)srow * ldb + k0);
    async_ld16(bs + 2048, Bptr + (long long)(srow + 64) * ldb + k0);
  };

  f32x4 zero = {0.f, 0.f, 0.f, 0.f};
  f32x4 acc[4][4];
#pragma unroll
  for (int i = 0; i < 4; ++i)
#pragma unroll
    for (int j = 0; j < 4; ++j) acc[i][j] = zero;

  // swizzled read col-chunk (per-lane constant): q4 ^ (row&3), row&3 == r15&3
  const int csw = ((q4 ^ (r15 & 3)) * 8);

  const int NT = K / BK;
  stage(0);
  if (NT > 1) stage(1);

  for (int kt = 0; kt < NT; ++kt) {
    if (kt + 1 < NT) asm volatile("s_waitcnt vmcnt(4)" ::: "memory");
    else             asm volatile("s_waitcnt vmcnt(0)" ::: "memory");
    __builtin_amdgcn_s_barrier();

    const u16* as = &As[kt & 1][0];
    const u16* bs = &Bs[kt & 1][0];

    short8 af[4], bf[4];
#pragma unroll
    for (int i = 0; i < 4; ++i)
      af[i] = *(const short8*)&as[(wm * 64 + i * 16 + r15) * BK + csw];
#pragma unroll
    for (int i = 0; i < 4; ++i)
      bf[i] = *(const short8*)&bs[(wn * 64 + i * 16 + r15) * BK + csw];

    __builtin_amdgcn_s_setprio(1);
#pragma unroll
    for (int i = 0; i < 4; ++i)
#pragma unroll
      for (int j = 0; j < 4; ++j)
        acc[i][j] = __builtin_amdgcn_mfma_f32_16x16x32_bf16(af[i], bf[j], acc[i][j], 0, 0, 0);
    __builtin_amdgcn_s_setprio(0);

    __builtin_amdgcn_s_barrier();
    if (kt + 2 < NT) stage(kt + 2);   // into buf[kt&1], fully read past barrier
  }

  // epilogue: C/D layout col = lane&15, row = q4*4 + reg  [e2e-verified]
#pragma unroll
  for (int i = 0; i < 4; ++i) {
#pragma unroll
    for (int j = 0; j < 4; ++j) {
      const int col = tileN + wn * 64 + j * 16 + r15;
#pragma unroll
      for (int r = 0; r < 4; ++r) {
        const int row = tileM + wm * 64 + i * 16 + q4 * 4 + r;
        const long long idx = (long long)blockIdx.z * sCz + (long long)row * ldc + col;
        const float val = acc[i][j][r] * scale;
        if (store_f32) ((float*)Cv)[idx] = val;
        else           ((u16*)Cv)[idx] = f2bf(val);
      }
    }
  }
}

// ---------------------------------------------------------------------------
// 256x256 / BK=64 / 8-wave (2Mx4N) / 512-thread GEMM (scores).
// Schedule per K-tile: vmcnt(4)+barrier | stage B(j+1) | read bf(all) +
// af(qm=0) | 32 MFMA | read af(qm=1) | 32 MFMA | barrier | stage A(j+2).
// (row&7)<<4 XOR swizzle via pre-swizzled global source + swizzled ds_read.
// ---------------------------------------------------------------------------
__global__ __launch_bounds__(512)
void gemm256_bt(const u16* __restrict__ A, const u16* __restrict__ Bt,
                u16* __restrict__ C, int K, int lda, int ldb, int ldc,
                long long sAz, long long sBz, long long sCz, float scale) {
  __shared__ u16 smem[65536];  // 128 KiB

  // T1: bijective XCD swizzle over the whole grid (nwg=512, %8==0).
  const int nwg = gridDim.x * gridDim.y * gridDim.z;
  const int lin = (blockIdx.z * gridDim.y + blockIdx.y) * gridDim.x + blockIdx.x;
  const int chunk = nwg >> 3;
  const int swz = (lin & 7) * chunk + (lin >> 3);
  const int bx = swz % gridDim.x;
  const int t1 = swz / gridDim.x;
  const int by = t1 % gridDim.y;
  const int bz = t1 / gridDim.y;

  A  += (long long)bz * sAz;
  Bt += (long long)bz * sBz;
  const long long cbase = (long long)bz * sCz;

  const int tid  = threadIdx.x;
  const int wid  = tid >> 6;
  const int lane = tid & 63;
  const int wm   = wid >> 2;       // 0..1: wave M-half
  const int wn   = wid & 3;        // 0..3: wave N-quarter
  const int r15  = lane & 15;
  const int q4   = lane >> 4;

  const int tileM = by * 256;
  const int tileN = bx * 256;

  const int srow = tid >> 3;                        // 0..63
  const int scol = ((tid & 7) ^ (srow & 7)) * 8;    // pre-swizzled source col

  const u16* Ap = A  + (long long)(tileM + srow) * lda + scol;
  const u16* Bp = Bt + (long long)(tileN + srow) * ldb + scol;

  auto stageA = [&](int kt, int half) {
    u16* dst = &smem[(kt & 1) * 32768 + half * 8192 + tid * 8];
    const u16* s = Ap + (long long)(half * 128) * lda + kt * 64;
    async_ld16(dst,        s);
    async_ld16(dst + 4096, s + 64 * lda);
  };
  auto stageB = [&](int kt, int half) {
    u16* dst = &smem[(kt & 1) * 32768 + 16384 + half * 8192 + tid * 8];
    const u16* s = Bp + (long long)(half * 128) * ldb + kt * 64;
    async_ld16(dst,        s);
    async_ld16(dst + 4096, s + 64 * ldb);
  };

  const int csw0 = (q4 * 8)      ^ ((r15 & 7) * 8);  // kh=0
  const int csw1 = (32 + q4 * 8) ^ ((r15 & 7) * 8);  // kh=1
  const u16* Aw = &smem[wm * 8192];
  const u16* Bw = &smem[16384 + (wn >> 1) * 8192 + (wn & 1) * 4096];

  f32x4 acc[8][4];
#pragma unroll
  for (int i = 0; i < 8; ++i)
#pragma unroll
    for (int j = 0; j < 4; ++j) acc[i][j] = (f32x4){0.f, 0.f, 0.f, 0.f};

  const int NT = K >> 6;

  stageA(0, 0); stageA(0, 1); stageB(0, 0); stageB(0, 1);
  if (NT > 1) { stageA(1, 0); stageA(1, 1); }

  for (int j = 0; j < NT; ++j) {
    if (j + 1 < NT) asm volatile("s_waitcnt vmcnt(4)" ::: "memory");
    else            asm volatile("s_waitcnt vmcnt(0)" ::: "memory");
    __builtin_amdgcn_s_barrier();

    const u16* Ad = Aw + (j & 1) * 32768;
    const u16* Bd = Bw + (j & 1) * 32768;

    if (j + 1 < NT) { stageB(j + 1, 0); stageB(j + 1, 1); }

    short8 af[4][2], bf0[2][2], bf1[2][2];
#pragma unroll
    for (int n2 = 0; n2 < 2; ++n2) {
      const int rb0 = (n2 * 16 + r15) * 64;
      const int rb1 = ((2 + n2) * 16 + r15) * 64;
      bf0[n2][0] = *(const short8*)&Bd[rb0 + csw0];
      bf0[n2][1] = *(const short8*)&Bd[rb0 + csw1];
      bf1[n2][0] = *(const short8*)&Bd[rb1 + csw0];
      bf1[n2][1] = *(const short8*)&Bd[rb1 + csw1];
    }
#pragma unroll
    for (int m2 = 0; m2 < 4; ++m2) {
      const int rb = (m2 * 16 + r15) * 64;
      af[m2][0] = *(const short8*)&Ad[rb + csw0];
      af[m2][1] = *(const short8*)&Ad[rb + csw1];
    }

    __builtin_amdgcn_s_setprio(1);
#pragma unroll
    for (int m2 = 0; m2 < 4; ++m2)
#pragma unroll
      for (int n2 = 0; n2 < 2; ++n2) {
        f32x4 c0 = acc[m2][n2];
        c0 = __builtin_amdgcn_mfma_f32_16x16x32_bf16(af[m2][0], bf0[n2][0], c0, 0, 0, 0);
        c0 = __builtin_amdgcn_mfma_f32_16x16x32_bf16(af[m2][1], bf0[n2][1], c0, 0, 0, 0);
        acc[m2][n2] = c0;
        f32x4 c1 = acc[m2][2 + n2];
        c1 = __builtin_amdgcn_mfma_f32_16x16x32_bf16(af[m2][0], bf1[n2][0], c1, 0, 0, 0);
        c1 = __builtin_amdgcn_mfma_f32_16x16x32_bf16(af[m2][1], bf1[n2][1], c1, 0, 0, 0);
        acc[m2][2 + n2] = c1;
      }
    __builtin_amdgcn_s_setprio(0);

#pragma unroll
    for (int m2 = 0; m2 < 4; ++m2) {
      const int rb = ((4 + m2) * 16 + r15) * 64;
      af[m2][0] = *(const short8*)&Ad[rb + csw0];
      af[m2][1] = *(const short8*)&Ad[rb + csw1];
    }

    __builtin_amdgcn_s_setprio(1);
#pragma unroll
    for (int m2 = 0; m2 < 4; ++m2)
#pragma unroll
      for (int n2 = 0; n2 < 2; ++n2) {
        f32x4 c0 = acc[4 + m2][n2];
        c0 = __builtin_amdgcn_mfma_f32_16x16x32_bf16(af[m2][0], bf0[n2][0], c0, 0, 0, 0);
        c0 = __builtin_amdgcn_mfma_f32_16x16x32_bf16(af[m2][1], bf0[n2][1], c0, 0, 0, 0);
        acc[4 + m2][n2] = c0;
        f32x4 c1 = acc[4 + m2][2 + n2];
        c1 = __builtin_amdgcn_mfma_f32_16x16x32_bf16(af[m2][0], bf1[n2][0], c1, 0, 0, 0);
        c1 = __builtin_amdgcn_mfma_f32_16x16x32_bf16(af[m2][1], bf1[n2][1], c1, 0, 0, 0);
        acc[4 + m2][2 + n2] = c1;
      }
    __builtin_amdgcn_s_setprio(0);

    __builtin_amdgcn_s_barrier();
    if (j + 2 < NT) { stageA(j + 2, 0); stageA(j + 2, 1); }  // into buf[cur]
  }

  const int crow = tileM + wm * 128 + q4 * 4;
  const int ccol = tileN + wn * 64 + r15;
#pragma unroll
  for (int mi = 0; mi < 8; ++mi)
#pragma unroll
    for (int nj = 0; nj < 4; ++nj)
#pragma unroll
      for (int r = 0; r < 4; ++r) {
        const long long row = crow + mi * 16 + r;
        C[cbase + row * ldc + (ccol + nj * 16)] = f2bf(acc[mi][nj][r] * scale);
      }
}

// In-place row softmax over 4096 bf16 columns. grid = rows, block = 256.
__global__ __launch_bounds__(256)
void softmax_rows(u16* __restrict__ S) {
  const int tid = threadIdx.x;
  u16* rp = S + (long long)blockIdx.x * 4096;

  uint4 a = ((const uint4*)rp)[tid * 2];
  uint4 b = ((const uint4*)rp)[tid * 2 + 1];
  unsigned w[8] = {a.x, a.y, a.z, a.w, b.x, b.y, b.z, b.w};
  float v[16];
#pragma unroll
  for (int i = 0; i < 8; ++i) {
    v[2 * i]     = __uint_as_float(w[i] << 16);
    v[2 * i + 1] = __uint_as_float(w[i] & 0xFFFF0000u);
  }

  float m = v[0];
#pragma unroll
  for (int i = 1; i < 16; ++i) m = fmaxf(m, v[i]);
#pragma unroll
  for (int o = 32; o > 0; o >>= 1) m = fmaxf(m, __shfl_xor(m, o));
  __shared__ float redm[4];
  __shared__ float reds[4];
  const int wave = tid >> 6;
  if ((tid & 63) == 0) redm[wave] = m;
  __syncthreads();
  m = fmaxf(fmaxf(redm[0], redm[1]), fmaxf(redm[2], redm[3]));

  float s = 0.f;
#pragma unroll
  for (int i = 0; i < 16; ++i) {
    v[i] = __expf(v[i] - m);
    s += v[i];
  }
#pragma unroll
  for (int o = 32; o > 0; o >>= 1) s += __shfl_xor(s, o);
  if ((tid & 63) == 0) reds[wave] = s;
  __syncthreads();
  s = (reds[0] + reds[1]) + (reds[2] + reds[3]);
  const float inv = 1.0f / s;

#pragma unroll
  for (int i = 0; i < 8; ++i)
    w[i] = (unsigned)f2bf(v[2 * i] * inv) | ((unsigned)f2bf(v[2 * i + 1] * inv) << 16);
  uint4 oa = {w[0], w[1], w[2], w[3]};
  uint4 ob = {w[4], w[5], w[6], w[7]};
  ((uint4*)rp)[tid * 2] = oa;
  ((uint4*)rp)[tid * 2 + 1] = ob;
}

extern "C" void kernel_launch(void* const* d_in, const int* in_sizes, int n_in,
                              void* d_out, int out_size, void* d_ws, size_t ws_size,
                              hipStream_t stream) {
  const float* x  = (const float*)d_in[0];   // (2,4096,1024) fp32, batch-major
  const float* Wq = (const float*)d_in[1];   // (1024,1024) fp32 (out,in)
  const float* Wk = (const float*)d_in[2];
  const float* Wv = (const float*)d_in[3];
  const float* Wo = (const float*)d_in[4];
  float* out = (float*)d_out;                // (2,4096,1024) FP32

  // ws layout (u16 units) — 136 MiB total
  u16* xb  = (u16*)d_ws;                     // 8192x1024
  u16* Wqb = xb  + 8388608;                  // 1024x1024
  u16* Wkb = Wqb + 1048576;                  // contiguous after Wqb!
  u16* Wvb = Wkb + 1048576;
  u16* Wob = Wvb + 1048576;
  u16* QKp = Wob + 1048576;                  // 8192x2048: Q cols 0-1023, Kp 1024+
  u16* Vt  = QKp + 16777216;                 // 1024x8192 (Vt[e][b*4096+l])
  u16* S   = Vt  + 8388608;                  // 2 x 4096x4096
  u16* O   = QKp;                            // alias: QKp dead after scores GEMM

  const dim3 blk(256);

  // 0: casts (once)
  cast_f32_bf16<<<dim3(4096), blk, 0, stream>>>(x,  xb,  8388608);
  cast_f32_bf16<<<dim3(512),  blk, 0, stream>>>(Wq, Wqb, 1048576);
  cast_f32_bf16<<<dim3(512),  blk, 0, stream>>>(Wk, Wkb, 1048576);
  cast_f32_bf16<<<dim3(512),  blk, 0, stream>>>(Wv, Wvb, 1048576);
  cast_f32_bf16<<<dim3(512),  blk, 0, stream>>>(Wo, Wob, 1048576);

  // 1: QKp = x @ [Wq;Wk]^T   (M=8192, N=2048, K=1024), 1024 blocks
  gemm_bt<<<dim3(16, 64, 1), blk, 0, stream>>>(xb, Wqb, QKp, 1024, 1024, 1024, 2048,
                                               0, 0, 0, 1.f, 0);
  // 2: Vt = Wv@x^T   (M=1024, N=8192, K=1024) -> ldc=8192, 512 blocks
  gemm_bt<<<dim3(64, 8, 1), blk, 0, stream>>>(Wvb, xb, Vt, 1024, 1024, 1024, 8192,
                                              0, 0, 0, 1.f, 0);
  // 3: S_z = Q_z @ Kp_z^T / 32   (M=N=4096, K=1024), z=2 — 256^2, 512 blocks
  gemm256_bt<<<dim3(16, 16, 2), dim3(512), 0, stream>>>(
      QKp, QKp + 1024, S, 1024, 2048, 2048, 4096,
      8388608LL, 8388608LL, 16777216LL, 0.03125f);
  // 4: softmax in place, 8192 rows
  softmax_rows<<<dim3(8192), blk, 0, stream>>>(S);
  // 5: O_z = P_z @ V_z == BT(A=S_z, Bt=Vt+z*4096, ldb=8192) -> O, 512 blocks
  gemm_bt<<<dim3(8, 32, 2), blk, 0, stream>>>(S, Vt, O, 4096, 4096, 8192, 1024,
                                              16777216LL, 4096LL, 4194304LL, 1.f, 0);
  // 6: out = O @ Wo^T   (M=8192, N=1024, K=1024), FP32 store, 512 blocks
  gemm_bt<<<dim3(8, 64, 1), blk, 0, stream>>>(O, Wob, out, 1024, 1024, 1024, 1024,
                                              0, 0, 0, 1.f, 1);
}